// Round 9
// baseline (267.174 us; speedup 1.0000x reference)
//
#include <hip/hip_runtime.h>
#include <math.h>

// ---------------------------------------------------------------------------
// Attn_14920716386547 R21: launch fusion WITHOUT hipLaunchCooperativeKernel.
// R20 post-mortem: coop version failed with absmax ~= max|ref| -> launches
// likely errored (unchecked). Suspect: runtime co-residency check for 512
// blocks x 71,680B LDS (143KB/CU) rejected; also Co aliased __restrict__ Qg.
// R21: manual grid barrier (device-scope atomicAdd + __threadfence, G16) in
// NORMAL launches, with co-residency guaranteed by construction:
//  L1 cvt->qkv: 384 blk x 256 thr, lb(256,2) (VGPR cap 256, LDS 16K -> 2/CU
//     trivially resident). 2 qkv jobs/block {bx,bx+384} (same bn: 384%24==0).
//  L2 attn->out: 256 blk x 512 thr, plain lb(512) -> 1 blk/CU always
//     resident. 2 attn jobs paired (qt,15-qt) balanced -> barrier -> 2 out
//     tiles. No __restrict__ on aliased Qg/Kg/Co.
// Barrier slots at ws+24MiB, zeroed via capture-safe hipMemsetAsync.
// Fallback (small ws): R19 4-kernel chain (shared bodies).
// ws (halves): Vth [0,4M) | Xh/Og overlay [4M,8M) | Wqkvh [8M,11M) |
//   Woh [11M,12M) | barrier @ byte 25165824. d_out: Qh|Kh scratch.
// ---------------------------------------------------------------------------

typedef _Float16 f16x8 __attribute__((ext_vector_type(8)));
typedef _Float16 f16x4 __attribute__((ext_vector_type(4)));
typedef _Float16 f16x2 __attribute__((ext_vector_type(2)));
typedef __attribute__((ext_vector_type(4))) float f32x4;
typedef __attribute__((ext_vector_type(16))) float f32x16;

#define MFMA16(a, b, c) __builtin_amdgcn_mfma_f32_16x16x32_f16(a, b, c, 0, 0, 0)
#define MFMA32(a, b, c) __builtin_amdgcn_mfma_f32_32x32x16_f16(a, b, c, 0, 0, 0)
#define QSCALE 0.18033688f /* 0.125 * log2(e): attention runs in exp2 domain */

__device__ __forceinline__ void async16(const void* g, void* l) {
  __builtin_amdgcn_global_load_lds(
      (const __attribute__((address_space(1))) unsigned int*)g,
      (__attribute__((address_space(3))) unsigned int*)l, 16, 0, 0);
}

__device__ __forceinline__ f16x2 pk2(float x, float y) {
  return __builtin_bit_cast(f16x2, __builtin_amdgcn_cvt_pkrtz(x, y));
}

__device__ __forceinline__ f16x8 cvt8(const float* __restrict__ p) {
  float4 a = *(const float4*)p;
  float4 b = *(const float4*)(p + 4);
  f16x2 p0 = pk2(a.x, a.y), p1 = pk2(a.z, a.w);
  f16x2 p2 = pk2(b.x, b.y), p3 = pk2(b.z, b.w);
  f16x8 h;
  h[0] = p0[0]; h[1] = p0[1]; h[2] = p1[0]; h[3] = p1[1];
  h[4] = p2[0]; h[5] = p2[1]; h[6] = p3[0]; h[7] = p3[1];
  return h;
}

// ---- manual grid barrier: one-shot, device-scope (G16, m20) ---------------
__device__ __forceinline__ void gbar(unsigned* cnt, unsigned* flag,
                                     unsigned nblk) {
  __syncthreads();                       // block's stores drained (vmcnt)
  if (threadIdx.x == 0) {
    __threadfence();                     // release: writeback local L2
    unsigned prev = atomicAdd(cnt, 1u);
    if (prev + 1 == nblk) {
      atomicExch(flag, 1u);              // release the pack
    } else {
      while (atomicAdd(flag, 0u) == 0u) __builtin_amdgcn_s_sleep(2);
    }
    __threadfence();                     // acquire: invalidate stale lines
  }
  __syncthreads();
}

// ---- convert helper: vec8 chunk i of the X|Wq|Wk|Wv|Wo concatenation ------
__device__ __forceinline__ void cvt_chunk(
    size_t i, const float* __restrict__ X, const float* __restrict__ Wq,
    const float* __restrict__ Wk, const float* __restrict__ Wv,
    const float* __restrict__ Wo, _Float16* __restrict__ Xh,
    _Float16* __restrict__ Wqkvh, _Float16* __restrict__ Woh) {
  const float* src; _Float16* dst; size_t off;
  if (i < 4194304u)      { src = X;  dst = Xh;              off = i; }
  else if (i < 5242880u) { src = Wq; dst = Wqkvh;           off = i - 4194304u; }
  else if (i < 6291456u) { src = Wk; dst = Wqkvh + 1048576; off = i - 5242880u; }
  else if (i < 7340032u) { src = Wv; dst = Wqkvh + 2097152; off = i - 6291456u; }
  else                   { src = Wo; dst = Woh;             off = i - 7340032u; }
  *(f16x8*)(dst + off) = cvt8(src + off);
}

// ---- fp32 -> fp16 convert (fallback path only): X into Xh -----------------
__global__ void convert_all(const float* __restrict__ X, _Float16* __restrict__ Xh) {
  size_t i = ((size_t)blockIdx.x * 256 + threadIdx.x) * 8;
  *(f16x8*)(Xh + i) = cvt8(X + i);
}

// ---- qkv GEMM body: m97 recipe. 128x128, BK=32, async16, unpadded ---------
__device__ __forceinline__ void qkv_body(
    _Float16* As, _Float16* Bs, const _Float16* __restrict__ Xh,
    const _Float16* __restrict__ Wh, _Float16* __restrict__ Qh,
    _Float16* __restrict__ Kh, _Float16* __restrict__ Vth, int bn, int bm) {
  const int tid = threadIdx.x;
  const int wave = tid >> 6, lane = tid & 63;
  const int quad = lane >> 4, l16 = lane & 15;
  const int wm = (wave >> 1) * 64, wn = (wave & 1) * 64;
  const int mat = bn >> 3;                       // 0=Q 1=K 2=V (block-uniform)

  const int r0 = tid >> 2, cc0 = (tid & 3) * 8;
  const int r1 = (tid + 256) >> 2;
  const _Float16* gA0 = &Xh[(size_t)(bm * 128 + r0) * 1024 + cc0];
  const _Float16* gA1 = &Xh[(size_t)(bm * 128 + r1) * 1024 + cc0];
  const _Float16* gB0 = &Wh[(size_t)(bn * 128 + r0) * 1024 + cc0];
  const _Float16* gB1 = &Wh[(size_t)(bn * 128 + r1) * 1024 + cc0];

  f32x4 acc[4][4] = {};

  for (int k0 = 0; k0 < 1024; k0 += 32) {
    __syncthreads();                     // all waves done reading prev tile
    async16(gA0 + k0, &As[(wave * 64) * 8]);
    async16(gA1 + k0, &As[(256 + wave * 64) * 8]);
    async16(gB0 + k0, &Bs[(wave * 64) * 8]);
    async16(gB1 + k0, &Bs[(256 + wave * 64) * 8]);
    __syncthreads();                     // vmcnt drain (compiler-inserted)
    f16x8 af[4], bf[4];
#pragma unroll
    for (int t = 0; t < 4; ++t) {
      af[t] = *(const f16x8*)&As[(wm + t * 16 + l16) * 32 + quad * 8];
      bf[t] = *(const f16x8*)&Bs[(wn + t * 16 + l16) * 32 + quad * 8];
    }
#pragma unroll
    for (int mt = 0; mt < 4; ++mt)
#pragma unroll
      for (int nt = 0; nt < 4; ++nt)
        acc[mt][nt] = MFMA16(af[mt], bf[nt], acc[mt][nt]);
  }

  // C-layout: col = l16, row = quad*4 + r  [verified m89/m91]
#pragma unroll
  for (int mt = 0; mt < 4; ++mt) {
    int m_base = bm * 128 + wm + mt * 16 + quad * 4;
    int b = m_base >> 11, sb = m_base & 2047;
#pragma unroll
    for (int nt = 0; nt < 4; ++nt) {
      int ob = (bn * 128 + wn + nt * 16) & 1023;
      int h = ob >> 6;
      int dh = (ob & 63) + l16;
      size_t bh = (size_t)(b * 16 + h);
      if (mat == 0) {
#pragma unroll
        for (int r = 0; r < 4; ++r)
          Qh[(bh * 2048 + sb + r) * 64 + dh] = (_Float16)(acc[mt][nt][r] * QSCALE);
      } else if (mat == 1) {
#pragma unroll
        for (int r = 0; r < 4; ++r)
          Kh[(bh * 2048 + sb + r) * 64 + dh] = (_Float16)acc[mt][nt][r];
      } else {
        f16x4 pk;
        pk[0] = (_Float16)acc[mt][nt][0];
        pk[1] = (_Float16)acc[mt][nt][1];
        pk[2] = (_Float16)acc[mt][nt][2];
        pk[3] = (_Float16)acc[mt][nt][3];
        *(f16x4*)&Vth[(bh * 64 + dh) * 2048 + sb] = pk;
      }
    }
  }
}

// ---- LAUNCH 1 (big path): convert -> manual barrier -> 2 qkv tiles --------
__global__ __launch_bounds__(256, 2) void fused_cvt_qkv(
    const float* __restrict__ X, const float* __restrict__ Wq,
    const float* __restrict__ Wk, const float* __restrict__ Wv,
    const float* __restrict__ Wo, _Float16* __restrict__ Xh,
    _Float16* __restrict__ Wqkvh, _Float16* __restrict__ Woh,
    _Float16* __restrict__ Qh, _Float16* __restrict__ Kh,
    _Float16* __restrict__ Vth, unsigned* bar) {
  __shared__ _Float16 As[128 * 32];
  __shared__ _Float16 Bs[128 * 32];
  const int bx = (int)blockIdx.x;           // 384 blocks
  // stage 1: convert all 8.4M floats (1,048,576 vec8 chunks, stride 98,304)
  for (unsigned c = bx * 256 + threadIdx.x; c < 1048576u; c += 98304u)
    cvt_chunk((size_t)c * 8, X, Wq, Wk, Wv, Wo, Xh, Wqkvh, Woh);
  gbar(bar + 0, bar + 1, 384);
  // stage 2: 768 qkv tiles, 2 per block; same bn both (384 % 24 == 0)
  qkv_body(As, Bs, Xh, Wqkvh, Qh, Kh, Vth, bx % 24, bx / 24);
  qkv_body(As, Bs, Xh, Wqkvh, Qh, Kh, Vth, bx % 24, (bx + 384) / 24);
}

// ---- QKV GEMM fallback (small ws): R9 padded path, cvt in-loop ------------
__global__ __launch_bounds__(256) void gemm_qkv_f(
    const _Float16* __restrict__ Xh, const float* __restrict__ Wq,
    const float* __restrict__ Wk, const float* __restrict__ Wv,
    _Float16* __restrict__ Qh, _Float16* __restrict__ Kh,
    _Float16* __restrict__ Vth) {
  __shared__ _Float16 As[128 * 72];
  __shared__ _Float16 Bs[128 * 72];
  const int tid = threadIdx.x;
  const int wave = tid >> 6, lane = tid & 63;
  const int quad = lane >> 4, l16 = lane & 15;
  const int wm = (wave >> 1) * 64, wn = (wave & 1) * 64;
  const int bn = blockIdx.x, bm = blockIdx.y;
  const int mat = bn >> 3;
  const float* Bsrc = (mat == 0) ? Wq : (mat == 1) ? Wk : Wv;
  const int brow0 = (bn & 7) * 128;

  f32x4 acc[4][4] = {};

  for (int k0 = 0; k0 < 1024; k0 += 64) {
    __syncthreads();
#pragma unroll
    for (int j = 0; j < 4; ++j) {
      int idx = tid + j * 256;
      int row = idx >> 3, c8 = idx & 7;
      *(int4*)&As[row * 72 + c8 * 8] =
          *(const int4*)&Xh[(size_t)(bm * 128 + row) * 1024 + k0 + c8 * 8];
      *(f16x8*)&Bs[row * 72 + c8 * 8] =
          cvt8(&Bsrc[(size_t)(brow0 + row) * 1024 + k0 + c8 * 8]);
    }
    __syncthreads();
#pragma unroll
    for (int kc = 0; kc < 2; ++kc) {
      f16x8 af[4], bf[4];
#pragma unroll
      for (int t = 0; t < 4; ++t) {
        af[t] = *(const f16x8*)&As[(wm + t * 16 + l16) * 72 + kc * 32 + quad * 8];
        bf[t] = *(const f16x8*)&Bs[(wn + t * 16 + l16) * 72 + kc * 32 + quad * 8];
      }
#pragma unroll
      for (int mt = 0; mt < 4; ++mt)
#pragma unroll
        for (int nt = 0; nt < 4; ++nt)
          acc[mt][nt] = MFMA16(af[mt], bf[nt], acc[mt][nt]);
    }
  }

#pragma unroll
  for (int mt = 0; mt < 4; ++mt) {
    int m_base = bm * 128 + wm + mt * 16 + quad * 4;
    int b = m_base >> 11, sb = m_base & 2047;
#pragma unroll
    for (int nt = 0; nt < 4; ++nt) {
      int ob = (bn * 128 + wn + nt * 16) & 1023;
      int h = ob >> 6;
      int dh = (ob & 63) + l16;
      size_t bh = (size_t)(b * 16 + h);
      if (mat == 0) {
#pragma unroll
        for (int r = 0; r < 4; ++r)
          Qh[(bh * 2048 + sb + r) * 64 + dh] = (_Float16)(acc[mt][nt][r] * QSCALE);
      } else if (mat == 1) {
#pragma unroll
        for (int r = 0; r < 4; ++r)
          Kh[(bh * 2048 + sb + r) * 64 + dh] = (_Float16)acc[mt][nt][r];
      } else {
        f16x4 pk;
        pk[0] = (_Float16)acc[mt][nt][0];
        pk[1] = (_Float16)acc[mt][nt][1];
        pk[2] = (_Float16)acc[mt][nt][2];
        pk[3] = (_Float16)acc[mt][nt][3];
        *(f16x4*)&Vth[(bh * 64 + dh) * 2048 + sb] = pk;
      }
    }
  }
}

// ---- attention body (R19): 512 thr, 2 groups x 4 waves, kt%2==group,
//      T14 named-scalar prefetch, setprio, diag chunk skip ------------------
__device__ __forceinline__ void attn_body(
    _Float16* smem, const _Float16* Qg, const _Float16* Kg,
    const _Float16* __restrict__ Vtg, _Float16* __restrict__ Og,
    int bh, int qt) {
  const int q0 = qt * 128;
  const int tid = threadIdx.x;
  const int group = tid >> 8;
  const int tidg = tid & 255;
  const int wv = (tid >> 6) & 3;
  const int lane = tid & 63;
  const int l31 = lane & 31, hl = lane >> 5;
  const int b = bh >> 4, h = bh & 15;
  const int qrow = q0 + wv * 32 + l31;

  _Float16* Kl = smem + group * (128 * 72 + 64 * 136);
  _Float16* Vl = Kl + 128 * 72;

  const _Float16* Qbase = Qg + ((size_t)bh * 2048 + qrow) * 64 + hl * 8;
  f16x8 aq[4];
#pragma unroll
  for (int t = 0; t < 4; ++t) aq[t] = *(const f16x8*)(Qbase + 16 * t);

  f32x16 oacc[2] = {};
  float la = 0.f, lb = 0.f;

  const int krow = tidg >> 3, kc8 = (tidg & 7) * 8;
  const int vrow = tidg >> 4, vc16 = (tidg & 15) * 8;
  const _Float16* gK = Kg + ((size_t)bh * 2048 + krow) * 64 + kc8;
  const _Float16* gV = Vtg + ((size_t)bh * 64 + vrow) * 2048 + vc16;

  int4 ka0, ka1, ka2, ka3, va0, va1, va2, va3;
  {
    const int ktp = (group <= qt) ? group : qt;
    const _Float16* kp = gK + (size_t)ktp * (128 * 64);
    const _Float16* vp = gV + (size_t)ktp * 128;
    ka0 = *(const int4*)(kp + 0 * 32 * 64);
    ka1 = *(const int4*)(kp + 1 * 32 * 64);
    ka2 = *(const int4*)(kp + 2 * 32 * 64);
    ka3 = *(const int4*)(kp + 3 * 32 * 64);
    va0 = *(const int4*)(vp + 0 * 16 * 2048);
    va1 = *(const int4*)(vp + 1 * 16 * 2048);
    va2 = *(const int4*)(vp + 2 * 16 * 2048);
    va3 = *(const int4*)(vp + 3 * 16 * 2048);
  }

  const int nmax = (qt + 2) >> 1;
  for (int it = 0; it < nmax; ++it) {
    const int kt = 2 * it + group;
    const bool valid = (kt <= qt);
    const int k0 = kt << 7;
    __syncthreads();
    *(int4*)&Kl[(krow + 0) * 72 + kc8] = ka0;
    *(int4*)&Kl[(krow + 32) * 72 + kc8] = ka1;
    *(int4*)&Kl[(krow + 64) * 72 + kc8] = ka2;
    *(int4*)&Kl[(krow + 96) * 72 + kc8] = ka3;
    *(int4*)&Vl[(vrow + 0) * 136 + vc16] = va0;
    *(int4*)&Vl[(vrow + 16) * 136 + vc16] = va1;
    *(int4*)&Vl[(vrow + 32) * 136 + vc16] = va2;
    *(int4*)&Vl[(vrow + 48) * 136 + vc16] = va3;
    {
      const int ktn = (kt + 2 <= qt) ? (kt + 2) : qt;   // clamped
      const _Float16* kp = gK + (size_t)ktn * (128 * 64);
      const _Float16* vp = gV + (size_t)ktn * 128;
      ka0 = *(const int4*)(kp + 0 * 32 * 64);
      ka1 = *(const int4*)(kp + 1 * 32 * 64);
      ka2 = *(const int4*)(kp + 2 * 32 * 64);
      ka3 = *(const int4*)(kp + 3 * 32 * 64);
      va0 = *(const int4*)(vp + 0 * 16 * 2048);
      va1 = *(const int4*)(vp + 1 * 16 * 2048);
      va2 = *(const int4*)(vp + 2 * 16 * 2048);
      va3 = *(const int4*)(vp + 3 * 16 * 2048);
    }
    __syncthreads();
    if (!valid) continue;

    const bool diag = (kt == qt);

#pragma unroll
    for (int s32t = 0; s32t < 4; ++s32t) {
      if (diag && s32t > wv) break;      // fully-masked chunks: exact skip
      f32x16 tv = {};
      __builtin_amdgcn_s_setprio(1);
#pragma unroll
      for (int t = 0; t < 4; ++t) {
        f16x8 kb = *(const f16x8*)&Kl[(s32t * 32 + l31) * 72 + t * 16 + hl * 8];
        tv = MFMA32(kb, aq[t], tv);
      }
      __builtin_amdgcn_s_setprio(0);
      int pkx[8];
#pragma unroll
      for (int i = 0; i < 8; ++i) {
        float x0 = tv[2 * i], x1 = tv[2 * i + 1];
        int kg = k0 + s32t * 32 + ((2 * i) & 3) + 8 * (i >> 1) + 4 * hl;
        if (diag) {
          if (kg > qrow) x0 = -1e30f;
          if (kg + 1 > qrow) x1 = -1e30f;
        }
        x0 = __builtin_amdgcn_exp2f(x0);
        x1 = __builtin_amdgcn_exp2f(x1);
        la += x0;
        lb += x1;
        pkx[i] = __builtin_bit_cast(int, pk2(x0, x1));
      }
      int s0 = hl ? pkx[0] : pkx[2];
      int s1 = hl ? pkx[1] : pkx[3];
      int s2 = hl ? pkx[4] : pkx[6];
      int s3 = hl ? pkx[5] : pkx[7];
      int r0 = __shfl_xor(s0, 32);
      int r1 = __shfl_xor(s1, 32);
      int r2 = __shfl_xor(s2, 32);
      int r3 = __shfl_xor(s3, 32);
      int4 f0, f1;
      f0.x = hl ? r0 : pkx[0];
      f0.y = hl ? r1 : pkx[1];
      f0.z = hl ? pkx[2] : r0;
      f0.w = hl ? pkx[3] : r1;
      f1.x = hl ? r2 : pkx[4];
      f1.y = hl ? r3 : pkx[5];
      f1.z = hl ? pkx[6] : r2;
      f1.w = hl ? pkx[7] : r3;
      f16x8 bp0 = __builtin_bit_cast(f16x8, f0);
      f16x8 bp1 = __builtin_bit_cast(f16x8, f1);
      __builtin_amdgcn_s_setprio(1);
#pragma unroll
      for (int d = 0; d < 2; ++d) {
        f16x8 vb0 = *(const f16x8*)&Vl[(d * 32 + l31) * 136 + s32t * 32 + hl * 8];
        f16x8 vb1 =
            *(const f16x8*)&Vl[(d * 32 + l31) * 136 + s32t * 32 + 16 + hl * 8];
        oacc[d] = MFMA32(vb0, bp0, oacc[d]);
        oacc[d] = MFMA32(vb1, bp1, oacc[d]);
      }
      __builtin_amdgcn_s_setprio(0);
    }
  }

  float lsum = la + lb;
  __syncthreads();
  float* mbuf = (float*)(smem + (128 * 72 + 64 * 136));
  float* slot = mbuf + (wv * 64 + lane) * 33;
  if (group == 1) {
#pragma unroll
    for (int d = 0; d < 2; ++d)
#pragma unroll
      for (int j = 0; j < 16; ++j) slot[d * 16 + j] = oacc[d][j];
    slot[32] = lsum;
  }
  __syncthreads();
  if (group == 0) {
#pragma unroll
    for (int d = 0; d < 2; ++d)
#pragma unroll
      for (int j = 0; j < 16; ++j) oacc[d][j] += slot[d * 16 + j];
    lsum += slot[32];
    lsum += __shfl_xor(lsum, 32);
    float inv = 1.0f / lsum;
#pragma unroll
    for (int d = 0; d < 2; ++d)
#pragma unroll
      for (int rq = 0; rq < 4; ++rq) {
        f16x4 o;
#pragma unroll
        for (int j = 0; j < 4; ++j)
          o[j] = (_Float16)(oacc[d][rq * 4 + j] * inv);
        int dh = d * 32 + 8 * rq + 4 * hl;
        *(f16x4*)&Og[(((size_t)b * 2048 + qrow) * 16 + h) * 64 + dh] = o;
      }
  }
}

// ---- standalone attn (fallback path) --------------------------------------
__global__ __launch_bounds__(512) void attn_kernel(
    const _Float16* __restrict__ Qg, const _Float16* __restrict__ Kg,
    const _Float16* __restrict__ Vtg, _Float16* __restrict__ Og) {
  __shared__ _Float16 smem[2 * (128 * 72 + 64 * 136)];
  attn_body(smem, Qg, Kg, Vtg, Og, (int)blockIdx.x, 15 - (int)blockIdx.y);
}

// ---- out-GEMM tile body (512-thr caller: waves 0-3 work, all barrier) -----
__device__ __forceinline__ void out_tile(
    _Float16* smem, const _Float16* Og, const _Float16* __restrict__ Woh,
    float* Co, int bn, int bm) {
  _Float16* As = smem;             // 128*32 halves
  _Float16* Bs = smem + 128 * 32;  // 64*32 halves
  const int tid = threadIdx.x;
  const int wave = tid >> 6, lane = tid & 63;
  const int quad = lane >> 4, l16 = lane & 15;
  const int wm = (wave >> 1) * 64, wn = (wave & 1) * 32;
  const bool act = (tid < 256);

  const int r0 = (tid & 255) >> 2, cc0 = (tid & 3) * 8;
  const int r1 = ((tid & 255) + 256) >> 2;
  const _Float16* gA0 = &Og[(size_t)(bm * 128 + r0) * 1024 + cc0];
  const _Float16* gA1 = &Og[(size_t)(bm * 128 + r1) * 1024 + cc0];
  const _Float16* gB0 = &Woh[(size_t)(bn * 64 + r0) * 1024 + cc0];

  f32x4 acc[4][2] = {};

  for (int k0 = 0; k0 < 1024; k0 += 32) {
    __syncthreads();
    if (act) {
      async16(gA0 + k0, &As[(wave * 64) * 8]);
      async16(gA1 + k0, &As[(256 + wave * 64) * 8]);
      async16(gB0 + k0, &Bs[(wave * 64) * 8]);
    }
    __syncthreads();
    if (act) {
      f16x8 af[4], bf[2];
#pragma unroll
      for (int t = 0; t < 4; ++t)
        af[t] = *(const f16x8*)&As[(wm + t * 16 + l16) * 32 + quad * 8];
#pragma unroll
      for (int t = 0; t < 2; ++t)
        bf[t] = *(const f16x8*)&Bs[(wn + t * 16 + l16) * 32 + quad * 8];
#pragma unroll
      for (int mt = 0; mt < 4; ++mt)
#pragma unroll
        for (int nt = 0; nt < 2; ++nt)
          acc[mt][nt] = MFMA16(af[mt], bf[nt], acc[mt][nt]);
    }
  }

  if (act) {
#pragma unroll
    for (int mt = 0; mt < 4; ++mt) {
      int m_base = bm * 128 + wm + mt * 16 + quad * 4;
#pragma unroll
      for (int nt = 0; nt < 2; ++nt) {
        int n = bn * 64 + wn + nt * 16 + l16;
#pragma unroll
        for (int r = 0; r < 4; ++r)
          Co[(size_t)(m_base + r) * 1024 + n] = acc[mt][nt][r];
      }
    }
  }
}

// ---- LAUNCH 2 (big path): 2 attn jobs -> barrier -> 2 out tiles -----------
// 256 blocks x 512 thr, 1 block/CU: co-residency unconditional.
// NOTE: Co aliases Qg/Kg (d_out) -> those params are NOT __restrict__.
__global__ __launch_bounds__(512) void fused_attn_out(
    const _Float16* Qg, const _Float16* Kg,
    const _Float16* __restrict__ Vtg, _Float16* __restrict__ Og,
    const _Float16* __restrict__ Woh, float* Co, unsigned* bar) {
  __shared__ _Float16 smem[2 * (128 * 72 + 64 * 136)];   // 71,680 B
  const int bx = (int)blockIdx.x;           // [0,256)
  // 512 attn jobs, 2/block, paired (qt, 15-qt) so every block does equal work
  {
    int j1 = bx;                 // qt in {8..15}
    attn_body(smem, Qg, Kg, Vtg, Og, j1 & 31, 15 - (j1 >> 5));
    int j2 = 511 - bx;           // qt in {0..7}, complementary
    attn_body(smem, Qg, Kg, Vtg, Og, j2 & 31, 15 - (j2 >> 5));
  }
  gbar(bar + 2, bar + 3, 256);
  // 512 out tiles, 2/block
  out_tile(smem, Og, Woh, Co, bx & 15, bx >> 4);
  out_tile(smem, Og, Woh, Co, (bx + 256) & 15, (bx + 256) >> 4);
}

// ---- output GEMM fallback (small ws): R9 padded path, cvt in-loop ---------
__global__ __launch_bounds__(256) void gemm_out_f(
    const _Float16* __restrict__ A, const float* __restrict__ Wo,
    float* __restrict__ Co) {
  __shared__ _Float16 As[128 * 72];
  __shared__ _Float16 Bs[64 * 72];
  const int tid = threadIdx.x;
  const int wave = tid >> 6, lane = tid & 63;
  const int quad = lane >> 4, l16 = lane & 15;
  const int wm = (wave >> 1) * 64, wn = (wave & 1) * 32;
  const int bn = blockIdx.x, bm = blockIdx.y;

  f32x4 acc[4][2] = {};

  for (int k0 = 0; k0 < 1024; k0 += 64) {
    __syncthreads();
#pragma unroll
    for (int j = 0; j < 4; ++j) {
      int idx = tid + j * 256;
      int row = idx >> 3, c8 = idx & 7;
      *(int4*)&As[row * 72 + c8 * 8] =
          *(const int4*)&A[(size_t)(bm * 128 + row) * 1024 + k0 + c8 * 8];
    }
#pragma unroll
    for (int j = 0; j < 2; ++j) {
      int idx = tid + j * 256;
      int row = idx >> 3, c8 = idx & 7;
      *(f16x8*)&Bs[row * 72 + c8 * 8] =
          cvt8(&Wo[(size_t)(bn * 64 + row) * 1024 + k0 + c8 * 8]);
    }
    __syncthreads();
#pragma unroll
    for (int kc = 0; kc < 2; ++kc) {
      f16x8 af[4], bf[2];
#pragma unroll
      for (int t = 0; t < 4; ++t)
        af[t] = *(const f16x8*)&As[(wm + t * 16 + l16) * 72 + kc * 32 + quad * 8];
#pragma unroll
      for (int t = 0; t < 2; ++t)
        bf[t] = *(const f16x8*)&Bs[(wn + t * 16 + l16) * 72 + kc * 32 + quad * 8];
#pragma unroll
      for (int mt = 0; mt < 4; ++mt)
#pragma unroll
        for (int nt = 0; nt < 2; ++nt)
          acc[mt][nt] = MFMA16(af[mt], bf[nt], acc[mt][nt]);
    }
  }

#pragma unroll
  for (int mt = 0; mt < 4; ++mt) {
    int m_base = bm * 128 + wm + mt * 16 + quad * 4;
#pragma unroll
    for (int nt = 0; nt < 2; ++nt) {
      int n = bn * 64 + wn + nt * 16 + l16;
#pragma unroll
      for (int r = 0; r < 4; ++r)
        Co[(size_t)(m_base + r) * 1024 + n] = acc[mt][nt][r];
    }
  }
}

extern "C" void kernel_launch(void* const* d_in, const int* in_sizes, int n_in,
                              void* d_out, int out_size, void* d_ws, size_t ws_size,
                              hipStream_t stream) {
  const float* X  = (const float*)d_in[0];
  const float* Wq = (const float*)d_in[1];
  const float* Wk = (const float*)d_in[2];
  const float* Wv = (const float*)d_in[3];
  const float* Wo = (const float*)d_in[4];
  float* out = (float*)d_out;

  _Float16* Qh    = (_Float16*)d_out;        // 4M halves (d_out scratch)
  _Float16* Kh    = Qh + 4194304;            // 4M halves
  _Float16* Vth   = (_Float16*)d_ws;         // 4M halves [b,h,dh,s]
  _Float16* Xh    = Vth + 4194304;           // 4M halves (Og overlay)
  _Float16* Og    = Xh;
  _Float16* Wqkvh = Xh + 4194304;            // 3M halves (big path only)
  _Float16* Woh   = Wqkvh + 3145728;         // 1M halves
  unsigned* bar   = (unsigned*)((char*)d_ws + 25165824);  // 4 slots

  const bool big = (ws_size >= 25165824u + 64u);

  if (big) {
    hipMemsetAsync(bar, 0, 64, stream);      // capture-safe
    fused_cvt_qkv<<<384, 256, 0, stream>>>(X, Wq, Wk, Wv, Wo, Xh, Wqkvh, Woh,
                                           Qh, Kh, Vth, bar);
    fused_attn_out<<<256, 512, 0, stream>>>(Qh, Kh, Vth, Og, Woh, out, bar);
  } else {
    convert_all<<<2048, 256, 0, stream>>>(X, Xh);
    gemm_qkv_f<<<dim3(24, 32), 256, 0, stream>>>(Xh, Wq, Wk, Wv, Qh, Kh, Vth);
    attn_kernel<<<dim3(32, 16), 512, 0, stream>>>(Qh, Kh, Vth, Og);
    gemm_out_f<<<dim3(16, 32), 256, 0, stream>>>(Og, Wo, out);
  }
}

// Round 10
// 172.368 us; speedup vs baseline: 1.5500x; 1.5500x over previous
//
#include <hip/hip_runtime.h>
#include <math.h>

// ---------------------------------------------------------------------------
// Attn_14920716386547 R22 = R16 RESTORED VERBATIM (best measured: 174.88us,
// Round-4 bench). Reversion log:
//  R17 (gemm_out async16 + attn setprio): 175.7 — flat.
//  R18 (barrier-free attn, direct L2 reads): 231 — staging is latency
//      conversion, not re-read avoidance. REVERTED.
//  R19 (R17 + diag chunk skip): 177.0 — flat.
//  R20 (coop-kernel fusion): FAILED correctness (launch rejected).
//  R21 (manual-barrier fusion): 267 — fusing stages with different optimal
//      grid shapes forces one stage to the other's geometry (cvt lost 10x
//      parallelism, qkv halved block count); fusion overhead saving << cost.
// Conclusion: R16 config is the converged point of this structure family.
// attn: LDS-staged, 2 groups x 4 waves, T14 named-scalar register prefetch
// (R16's win: attn 47.5 -> <43.7us). qkv: m97 async16 recipe. out: padded
// VGPR-staged 128x64. Remaining total-vs-kernel-sum gap (~60us) is harness
// dispatch overhead (fills/ramp), not kernel-addressable.
// ws (halves): Vth [0,4M) | Xh/Og overlay [4M,8M) | Wqkvh [8M,11M) |
//   Woh [11M,12M) (big path only). d_out: Qh|Kh scratch (dead before out).
// ---------------------------------------------------------------------------

typedef _Float16 f16x8 __attribute__((ext_vector_type(8)));
typedef _Float16 f16x4 __attribute__((ext_vector_type(4)));
typedef _Float16 f16x2 __attribute__((ext_vector_type(2)));
typedef __attribute__((ext_vector_type(4))) float f32x4;
typedef __attribute__((ext_vector_type(16))) float f32x16;

#define MFMA16(a, b, c) __builtin_amdgcn_mfma_f32_16x16x32_f16(a, b, c, 0, 0, 0)
#define MFMA32(a, b, c) __builtin_amdgcn_mfma_f32_32x32x16_f16(a, b, c, 0, 0, 0)
#define QSCALE 0.18033688f /* 0.125 * log2(e): attention runs in exp2 domain */

__device__ __forceinline__ void async16(const void* g, void* l) {
  // async global->LDS, 16 B/lane; l = wave-uniform base, lane scatters +16B
  __builtin_amdgcn_global_load_lds(
      (const __attribute__((address_space(1))) unsigned int*)g,
      (__attribute__((address_space(3))) unsigned int*)l, 16, 0, 0);
}

__device__ __forceinline__ f16x2 pk2(float x, float y) {
  return __builtin_bit_cast(f16x2, __builtin_amdgcn_cvt_pkrtz(x, y));
}

__device__ __forceinline__ f16x8 cvt8(const float* __restrict__ p) {
  float4 a = *(const float4*)p;
  float4 b = *(const float4*)(p + 4);
  f16x2 p0 = pk2(a.x, a.y), p1 = pk2(a.z, a.w);
  f16x2 p2 = pk2(b.x, b.y), p3 = pk2(b.z, b.w);
  f16x8 h;
  h[0] = p0[0]; h[1] = p0[1]; h[2] = p1[0]; h[3] = p1[1];
  h[4] = p2[0]; h[5] = p2[1]; h[6] = p3[0]; h[7] = p3[1];
  return h;
}

// ---- fp32 -> fp16 convert: X always; with grid=4096 also Wq|Wk|Wv|Wo ------
__global__ void convert_all(const float* __restrict__ X, const float* __restrict__ Wq,
                            const float* __restrict__ Wk, const float* __restrict__ Wv,
                            const float* __restrict__ Wo, _Float16* __restrict__ Xh,
                            _Float16* __restrict__ Wqkvh, _Float16* __restrict__ Woh) {
  size_t i = ((size_t)blockIdx.x * 256 + threadIdx.x) * 8;
  const float* src; _Float16* dst; size_t off;
  if (i < 4194304u)      { src = X;  dst = Xh;              off = i; }
  else if (i < 5242880u) { src = Wq; dst = Wqkvh;           off = i - 4194304u; }
  else if (i < 6291456u) { src = Wk; dst = Wqkvh + 1048576; off = i - 5242880u; }
  else if (i < 7340032u) { src = Wv; dst = Wqkvh + 2097152; off = i - 6291456u; }
  else                   { src = Wo; dst = Woh;             off = i - 7340032u; }
  *(f16x8*)(dst + off) = cvt8(src + off);
}

// ---- QKV GEMM big path: m97 recipe. 128x128, BK=32, async16, unpadded -----
__global__ __launch_bounds__(256) void gemm_qkv_a(
    const _Float16* __restrict__ Xh, const _Float16* __restrict__ Wh,
    _Float16* __restrict__ Qh, _Float16* __restrict__ Kh,
    _Float16* __restrict__ Vth) {
  __shared__ _Float16 As[128 * 32];   // unpadded (DMA dest), 8 KB
  __shared__ _Float16 Bs[128 * 32];
  const int tid = threadIdx.x;
  const int wave = tid >> 6, lane = tid & 63;
  const int quad = lane >> 4, l16 = lane & 15;
  const int wm = (wave >> 1) * 64, wn = (wave & 1) * 64;
  const int bn = blockIdx.x, bm = blockIdx.y;    // XCD = bn%8
  const int mat = bn >> 3;                       // 0=Q 1=K 2=V (block-uniform)

  // chunk c in [0,512): covers halves [c*8, c*8+8) = row c>>2, col (c&3)*8.
  // thread handles chunks tid and tid+256; wave-uniform LDS bases.
  const int r0 = tid >> 2, cc0 = (tid & 3) * 8;
  const int r1 = (tid + 256) >> 2, cc1 = (tid & 3) * 8;  // (tid+256)&3 == tid&3
  const _Float16* gA0 = &Xh[(size_t)(bm * 128 + r0) * 1024 + cc0];
  const _Float16* gA1 = &Xh[(size_t)(bm * 128 + r1) * 1024 + cc1];
  const _Float16* gB0 = &Wh[(size_t)(bn * 128 + r0) * 1024 + cc0];
  const _Float16* gB1 = &Wh[(size_t)(bn * 128 + r1) * 1024 + cc1];

  f32x4 acc[4][4] = {};

  for (int k0 = 0; k0 < 1024; k0 += 32) {
    __syncthreads();                     // all waves done reading prev tile
    async16(gA0 + k0, &As[(wave * 64) * 8]);
    async16(gA1 + k0, &As[(256 + wave * 64) * 8]);
    async16(gB0 + k0, &Bs[(wave * 64) * 8]);
    async16(gB1 + k0, &Bs[(256 + wave * 64) * 8]);
    __syncthreads();                     // vmcnt drain (compiler-inserted)
    f16x8 af[4], bf[4];
#pragma unroll
    for (int t = 0; t < 4; ++t) {
      af[t] = *(const f16x8*)&As[(wm + t * 16 + l16) * 32 + quad * 8];
      bf[t] = *(const f16x8*)&Bs[(wn + t * 16 + l16) * 32 + quad * 8];
    }
#pragma unroll
    for (int mt = 0; mt < 4; ++mt)
#pragma unroll
      for (int nt = 0; nt < 4; ++nt)
        acc[mt][nt] = MFMA16(af[mt], bf[nt], acc[mt][nt]);
  }

  // C-layout: col = l16, row = quad*4 + r  [verified m89/m91]
#pragma unroll
  for (int mt = 0; mt < 4; ++mt) {
    int m_base = bm * 128 + wm + mt * 16 + quad * 4;
    int b = m_base >> 11, sb = m_base & 2047;
#pragma unroll
    for (int nt = 0; nt < 4; ++nt) {
      int ob = (bn * 128 + wn + nt * 16) & 1023;
      int h = ob >> 6;
      int dh = (ob & 63) + l16;
      size_t bh = (size_t)(b * 16 + h);
      if (mat == 0) {
#pragma unroll
        for (int r = 0; r < 4; ++r)
          Qh[(bh * 2048 + sb + r) * 64 + dh] = (_Float16)(acc[mt][nt][r] * QSCALE);
      } else if (mat == 1) {
#pragma unroll
        for (int r = 0; r < 4; ++r)
          Kh[(bh * 2048 + sb + r) * 64 + dh] = (_Float16)acc[mt][nt][r];
      } else {
        f16x4 pk;
        pk[0] = (_Float16)acc[mt][nt][0];
        pk[1] = (_Float16)acc[mt][nt][1];
        pk[2] = (_Float16)acc[mt][nt][2];
        pk[3] = (_Float16)acc[mt][nt][3];
        *(f16x4*)&Vth[(bh * 64 + dh) * 2048 + sb] = pk;
      }
    }
  }
}

// ---- QKV GEMM fallback (small ws): R9 padded path, cvt in-loop ------------
__global__ __launch_bounds__(256) void gemm_qkv_f(
    const _Float16* __restrict__ Xh, const float* __restrict__ Wq,
    const float* __restrict__ Wk, const float* __restrict__ Wv,
    _Float16* __restrict__ Qh, _Float16* __restrict__ Kh,
    _Float16* __restrict__ Vth) {
  __shared__ _Float16 As[128 * 72];
  __shared__ _Float16 Bs[128 * 72];
  const int tid = threadIdx.x;
  const int wave = tid >> 6, lane = tid & 63;
  const int quad = lane >> 4, l16 = lane & 15;
  const int wm = (wave >> 1) * 64, wn = (wave & 1) * 64;
  const int bn = blockIdx.x, bm = blockIdx.y;
  const int mat = bn >> 3;
  const float* Bsrc = (mat == 0) ? Wq : (mat == 1) ? Wk : Wv;
  const int brow0 = (bn & 7) * 128;

  f32x4 acc[4][4] = {};

  for (int k0 = 0; k0 < 1024; k0 += 64) {
    __syncthreads();
#pragma unroll
    for (int j = 0; j < 4; ++j) {
      int idx = tid + j * 256;
      int row = idx >> 3, c8 = idx & 7;
      *(int4*)&As[row * 72 + c8 * 8] =
          *(const int4*)&Xh[(size_t)(bm * 128 + row) * 1024 + k0 + c8 * 8];
      *(f16x8*)&Bs[row * 72 + c8 * 8] =
          cvt8(&Bsrc[(size_t)(brow0 + row) * 1024 + k0 + c8 * 8]);
    }
    __syncthreads();
#pragma unroll
    for (int kc = 0; kc < 2; ++kc) {
      f16x8 af[4], bf[4];
#pragma unroll
      for (int t = 0; t < 4; ++t) {
        af[t] = *(const f16x8*)&As[(wm + t * 16 + l16) * 72 + kc * 32 + quad * 8];
        bf[t] = *(const f16x8*)&Bs[(wn + t * 16 + l16) * 72 + kc * 32 + quad * 8];
      }
#pragma unroll
      for (int mt = 0; mt < 4; ++mt)
#pragma unroll
        for (int nt = 0; nt < 4; ++nt)
          acc[mt][nt] = MFMA16(af[mt], bf[nt], acc[mt][nt]);
    }
  }

#pragma unroll
  for (int mt = 0; mt < 4; ++mt) {
    int m_base = bm * 128 + wm + mt * 16 + quad * 4;
    int b = m_base >> 11, sb = m_base & 2047;
#pragma unroll
    for (int nt = 0; nt < 4; ++nt) {
      int ob = (bn * 128 + wn + nt * 16) & 1023;
      int h = ob >> 6;
      int dh = (ob & 63) + l16;
      size_t bh = (size_t)(b * 16 + h);
      if (mat == 0) {
#pragma unroll
        for (int r = 0; r < 4; ++r)
          Qh[(bh * 2048 + sb + r) * 64 + dh] = (_Float16)(acc[mt][nt][r] * QSCALE);
      } else if (mat == 1) {
#pragma unroll
        for (int r = 0; r < 4; ++r)
          Kh[(bh * 2048 + sb + r) * 64 + dh] = (_Float16)acc[mt][nt][r];
      } else {
        f16x4 pk;
        pk[0] = (_Float16)acc[mt][nt][0];
        pk[1] = (_Float16)acc[mt][nt][1];
        pk[2] = (_Float16)acc[mt][nt][2];
        pk[3] = (_Float16)acc[mt][nt][3];
        *(f16x4*)&Vth[(bh * 64 + dh) * 2048 + sb] = pk;
      }
    }
  }
}

// ---- attention R16: 512 thr, 2 groups x 4 waves, kt%2==group,
//      T14 prefetch via 8 NAMED int4 scalars, unconditional clamped loads ---
__global__ __launch_bounds__(512) void attn_kernel(
    const _Float16* __restrict__ Qg, const _Float16* __restrict__ Kg,
    const _Float16* __restrict__ Vtg, _Float16* __restrict__ Og) {
  __shared__ _Float16 smem[2 * (128 * 72 + 64 * 136)];   // 71,680 B
  const int bh = blockIdx.x;               // XCD = bh % 8
  const int qt = 15 - (int)blockIdx.y;     // heavy tiles dispatched first
  const int q0 = qt * 128;
  const int tid = threadIdx.x;
  const int group = tid >> 8;
  const int tidg = tid & 255;
  const int wv = (tid >> 6) & 3;
  const int lane = tid & 63;
  const int l31 = lane & 31, hl = lane >> 5;
  const int b = bh >> 4, h = bh & 15;
  const int qrow = q0 + wv * 32 + l31;

  _Float16* Kl = smem + group * (128 * 72 + 64 * 136);
  _Float16* Vl = Kl + 128 * 72;

  const _Float16* Qbase = Qg + ((size_t)bh * 2048 + qrow) * 64 + hl * 8;
  f16x8 aq[4];
#pragma unroll
  for (int t = 0; t < 4; ++t) aq[t] = *(const f16x8*)(Qbase + 16 * t);

  f32x16 oacc[2] = {};
  float la = 0.f, lb = 0.f;                // split lsum dep chain

  // staging geometry (constant per thread): K row/col, V row/col
  const int krow = tidg >> 3, kc8 = (tidg & 7) * 8;
  const int vrow = tidg >> 4, vc16 = (tidg & 15) * 8;
  // per-thread global base pointers (tile kt at +kt*128*64 / +kt*128)
  const _Float16* gK = Kg + ((size_t)bh * 2048 + krow) * 64 + kc8;
  const _Float16* gV = Vtg + ((size_t)bh * 64 + vrow) * 2048 + vc16;

  // T14 prefetch regs: NAMED scalars (arrays went to scratch, R13/R14).
  // Loads always execute with tile index clamped to qt -> always in-bounds,
  // no partial-definition path, SROA promotes to VGPRs.
  int4 ka0, ka1, ka2, ka3, va0, va1, va2, va3;
  {
    const int ktp = (group <= qt) ? group : qt;
    const _Float16* kp = gK + (size_t)ktp * (128 * 64);
    const _Float16* vp = gV + (size_t)ktp * 128;
    ka0 = *(const int4*)(kp + 0 * 32 * 64);
    ka1 = *(const int4*)(kp + 1 * 32 * 64);
    ka2 = *(const int4*)(kp + 2 * 32 * 64);
    ka3 = *(const int4*)(kp + 3 * 32 * 64);
    va0 = *(const int4*)(vp + 0 * 16 * 2048);
    va1 = *(const int4*)(vp + 1 * 16 * 2048);
    va2 = *(const int4*)(vp + 2 * 16 * 2048);
    va3 = *(const int4*)(vp + 3 * 16 * 2048);
  }

  const int nmax = (qt + 2) >> 1;
  for (int it = 0; it < nmax; ++it) {
    const int kt = 2 * it + group;
    const bool valid = (kt <= qt);
    const int k0 = kt << 7;
    __syncthreads();                       // prev compute done reading LDS
    // write current tile into own group's buffer (unconditional; when
    // !valid the data is stale-but-safe and compute is skipped)
    *(int4*)&Kl[(krow + 0) * 72 + kc8] = ka0;
    *(int4*)&Kl[(krow + 32) * 72 + kc8] = ka1;
    *(int4*)&Kl[(krow + 64) * 72 + kc8] = ka2;
    *(int4*)&Kl[(krow + 96) * 72 + kc8] = ka3;
    *(int4*)&Vl[(vrow + 0) * 136 + vc16] = va0;
    *(int4*)&Vl[(vrow + 16) * 136 + vc16] = va1;
    *(int4*)&Vl[(vrow + 32) * 136 + vc16] = va2;
    *(int4*)&Vl[(vrow + 48) * 136 + vc16] = va3;
    {
      // issue NEXT tile's loads now -> latency hides under compute phase
      const int ktn = (kt + 2 <= qt) ? (kt + 2) : qt;   // clamped
      const _Float16* kp = gK + (size_t)ktn * (128 * 64);
      const _Float16* vp = gV + (size_t)ktn * 128;
      ka0 = *(const int4*)(kp + 0 * 32 * 64);
      ka1 = *(const int4*)(kp + 1 * 32 * 64);
      ka2 = *(const int4*)(kp + 2 * 32 * 64);
      ka3 = *(const int4*)(kp + 3 * 32 * 64);
      va0 = *(const int4*)(vp + 0 * 16 * 2048);
      va1 = *(const int4*)(vp + 1 * 16 * 2048);
      va2 = *(const int4*)(vp + 2 * 16 * 2048);
      va3 = *(const int4*)(vp + 3 * 16 * 2048);
    }
    __syncthreads();                       // LDS tile visible
    if (!valid) continue;

    const bool diag = (kt == qt);

#pragma unroll
    for (int s32t = 0; s32t < 4; ++s32t) {
      f32x16 tv = {};
#pragma unroll
      for (int t = 0; t < 4; ++t) {
        f16x8 kb = *(const f16x8*)&Kl[(s32t * 32 + l31) * 72 + t * 16 + hl * 8];
        tv = MFMA32(kb, aq[t], tv);
      }
      int pkx[8];
#pragma unroll
      for (int i = 0; i < 8; ++i) {
        float x0 = tv[2 * i], x1 = tv[2 * i + 1];
        int kg = k0 + s32t * 32 + ((2 * i) & 3) + 8 * (i >> 1) + 4 * hl;
        if (diag) {
          if (kg > qrow) x0 = -1e30f;
          if (kg + 1 > qrow) x1 = -1e30f;
        }
        x0 = __builtin_amdgcn_exp2f(x0);
        x1 = __builtin_amdgcn_exp2f(x1);
        la += x0;
        lb += x1;
        pkx[i] = __builtin_bit_cast(int, pk2(x0, x1));
      }
      int s0 = hl ? pkx[0] : pkx[2];
      int s1 = hl ? pkx[1] : pkx[3];
      int s2 = hl ? pkx[4] : pkx[6];
      int s3 = hl ? pkx[5] : pkx[7];
      int r0 = __shfl_xor(s0, 32);
      int r1 = __shfl_xor(s1, 32);
      int r2 = __shfl_xor(s2, 32);
      int r3 = __shfl_xor(s3, 32);
      int4 f0, f1;
      f0.x = hl ? r0 : pkx[0];
      f0.y = hl ? r1 : pkx[1];
      f0.z = hl ? pkx[2] : r0;
      f0.w = hl ? pkx[3] : r1;
      f1.x = hl ? r2 : pkx[4];
      f1.y = hl ? r3 : pkx[5];
      f1.z = hl ? pkx[6] : r2;
      f1.w = hl ? pkx[7] : r3;
      f16x8 bp0 = __builtin_bit_cast(f16x8, f0);
      f16x8 bp1 = __builtin_bit_cast(f16x8, f1);
#pragma unroll
      for (int d = 0; d < 2; ++d) {
        f16x8 vb0 = *(const f16x8*)&Vl[(d * 32 + l31) * 136 + s32t * 32 + hl * 8];
        f16x8 vb1 =
            *(const f16x8*)&Vl[(d * 32 + l31) * 136 + s32t * 32 + 16 + hl * 8];
        oacc[d] = MFMA32(vb0, bp0, oacc[d]);
        oacc[d] = MFMA32(vb1, bp1, oacc[d]);
      }
    }
  }

  float lsum = la + lb;
  __syncthreads();
  float* mbuf = (float*)(smem + (128 * 72 + 64 * 136));
  float* slot = mbuf + (wv * 64 + lane) * 33;
  if (group == 1) {
#pragma unroll
    for (int d = 0; d < 2; ++d)
#pragma unroll
      for (int j = 0; j < 16; ++j) slot[d * 16 + j] = oacc[d][j];
    slot[32] = lsum;
  }
  __syncthreads();
  if (group == 0) {
#pragma unroll
    for (int d = 0; d < 2; ++d)
#pragma unroll
      for (int j = 0; j < 16; ++j) oacc[d][j] += slot[d * 16 + j];
    lsum += slot[32];
    lsum += __shfl_xor(lsum, 32);
    float inv = 1.0f / lsum;
#pragma unroll
    for (int d = 0; d < 2; ++d)
#pragma unroll
      for (int rq = 0; rq < 4; ++rq) {
        f16x4 o;
#pragma unroll
        for (int j = 0; j < 4; ++j)
          o[j] = (_Float16)(oacc[d][rq * 4 + j] * inv);
        int dh = d * 32 + 8 * rq + 4 * hl;
        *(f16x4*)&Og[(((size_t)b * 2048 + qrow) * 16 + h) * 64 + dh] = o;
      }
  }
}

// ---- output GEMM (R9): 128x64 tiles, 512 blocks ---------------------------
template <int BH>
__global__ __launch_bounds__(256) void gemm_out(
    const _Float16* __restrict__ A, const float* __restrict__ Wo,
    const _Float16* __restrict__ Woh, float* __restrict__ Co) {
  __shared__ _Float16 As[128 * 72];
  __shared__ _Float16 Bs[64 * 72];
  const int tid = threadIdx.x;
  const int wave = tid >> 6, lane = tid & 63;
  const int quad = lane >> 4, l16 = lane & 15;
  const int wm = (wave >> 1) * 64, wn = (wave & 1) * 32;
  const int bn = blockIdx.x, bm = blockIdx.y;

  f32x4 acc[4][2] = {};

  for (int k0 = 0; k0 < 1024; k0 += 64) {
    __syncthreads();
#pragma unroll
    for (int j = 0; j < 4; ++j) {
      int idx = tid + j * 256;
      int row = idx >> 3, c8 = idx & 7;
      *(int4*)&As[row * 72 + c8 * 8] =
          *(const int4*)&A[(size_t)(bm * 128 + row) * 1024 + k0 + c8 * 8];
    }
#pragma unroll
    for (int j = 0; j < 2; ++j) {
      int idx = tid + j * 256;
      int row = idx >> 3, c8 = idx & 7;
      if (BH)
        *(int4*)&Bs[row * 72 + c8 * 8] =
            *(const int4*)&Woh[(size_t)(bn * 64 + row) * 1024 + k0 + c8 * 8];
      else
        *(f16x8*)&Bs[row * 72 + c8 * 8] =
            cvt8(&Wo[(size_t)(bn * 64 + row) * 1024 + k0 + c8 * 8]);
    }
    __syncthreads();
#pragma unroll
    for (int kc = 0; kc < 2; ++kc) {
      f16x8 af[4], bf[2];
#pragma unroll
      for (int t = 0; t < 4; ++t)
        af[t] = *(const f16x8*)&As[(wm + t * 16 + l16) * 72 + kc * 32 + quad * 8];
#pragma unroll
      for (int t = 0; t < 2; ++t)
        bf[t] = *(const f16x8*)&Bs[(wn + t * 16 + l16) * 72 + kc * 32 + quad * 8];
#pragma unroll
      for (int mt = 0; mt < 4; ++mt)
#pragma unroll
        for (int nt = 0; nt < 2; ++nt)
          acc[mt][nt] = MFMA16(af[mt], bf[nt], acc[mt][nt]);
    }
  }

#pragma unroll
  for (int mt = 0; mt < 4; ++mt) {
    int m_base = bm * 128 + wm + mt * 16 + quad * 4;
#pragma unroll
    for (int nt = 0; nt < 2; ++nt) {
      int n = bn * 64 + wn + nt * 16 + l16;
#pragma unroll
      for (int r = 0; r < 4; ++r)
        Co[(size_t)(m_base + r) * 1024 + n] = acc[mt][nt][r];
    }
  }
}

extern "C" void kernel_launch(void* const* d_in, const int* in_sizes, int n_in,
                              void* d_out, int out_size, void* d_ws, size_t ws_size,
                              hipStream_t stream) {
  const float* X  = (const float*)d_in[0];
  const float* Wq = (const float*)d_in[1];
  const float* Wk = (const float*)d_in[2];
  const float* Wv = (const float*)d_in[3];
  const float* Wo = (const float*)d_in[4];
  float* out = (float*)d_out;

  _Float16* Qh    = (_Float16*)d_out;        // 4M halves (d_out scratch)
  _Float16* Kh    = Qh + 4194304;            // 4M halves
  _Float16* Vth   = (_Float16*)d_ws;         // 4M halves [b,h,dh,s]
  _Float16* Xh    = Vth + 4194304;           // 4M halves (Og overlay)
  _Float16* Og    = Xh;
  _Float16* Wqkvh = Xh + 4194304;            // 3M halves (big path only)
  _Float16* Woh   = Wqkvh + 3145728;         // 1M halves

  const bool big = (ws_size >= 25165824u);

  convert_all<<<big ? 4096 : 2048, 256, 0, stream>>>(X, Wq, Wk, Wv, Wo,
                                                     Xh, Wqkvh, Woh);
  if (big)
    gemm_qkv_a<<<dim3(24, 32), 256, 0, stream>>>(Xh, Wqkvh, Qh, Kh, Vth);
  else
    gemm_qkv_f<<<dim3(24, 32), 256, 0, stream>>>(Xh, Wq, Wk, Wv, Qh, Kh, Vth);
  attn_kernel<<<dim3(32, 16), 512, 0, stream>>>(Qh, Kh, Vth, Og);
  if (big)
    gemm_out<1><<<dim3(16, 32), 256, 0, stream>>>(Og, Wo, Woh, out);
  else
    gemm_out<0><<<dim3(16, 32), 256, 0, stream>>>(Og, Wo, nullptr, out);
}